// Round 19
// baseline (378.572 us; speedup 1.0000x reference)
//
#include <hip/hip_runtime.h>
#include <math.h>

typedef unsigned short u16;
typedef __bf16 bf16x8 __attribute__((ext_vector_type(8)));
typedef float f32x4 __attribute__((ext_vector_type(4)));

// ---- all scratch in device globals: zero dependence on ws_size ----
__device__ u16   g_A_pack[16 * 512 * 32];  // bf16 conv weights, swizzled [ks][d][kl]
__device__ float g_st[16 * 512];
__device__ float g_eraw[16 * 4096];        // raw energies (pre-mask, pre-softmax)
__device__ float g_energ[16 * 4096];       // softmaxed attention
__device__ float g_data[16 * 1792];
__device__ float g_merged[16 * 1024];
__device__ float g_update[16 * 256];
__device__ float g_reset[16 * 256];
__device__ float g_i2s[16 * 256];
__device__ float g_hid[16 * 512];

__device__ __forceinline__ u16 f2bf(float f) {
    unsigned u = __float_as_uint(f);
    u = (u + 0x7FFFu + ((u >> 16) & 1u)) >> 16;
    return (u16)u;
}
__device__ __forceinline__ float bf2f(u16 u) {
    return __uint_as_float(((unsigned)u) << 16);
}
__device__ __forceinline__ float fast_tanh(float x) {
    return 1.0f - 2.0f / (__expf(2.0f * x) + 1.0f);
}
__device__ __forceinline__ float sigmoidf_(float x) {
    return 1.0f / (1.0f + __expf(-x));
}

// ---- fused pre-pass: [0,1024) weight pack | [1024,3072) st GEMV | [3072,3088) e0 ----
__global__ void k_pre(const float* __restrict__ w_wt, const float* __restrict__ w_cwt,
                      const float* __restrict__ w_condwt, const float* __restrict__ state,
                      const float* __restrict__ context, const float* __restrict__ cond_mem,
                      const float* __restrict__ w_state, const float* __restrict__ w_ctx,
                      const float* __restrict__ w_cond, const int* __restrict__ label,
                      const float* __restrict__ embed_table) {
    int bid = blockIdx.x;
    if (bid < 1024) {
        int idx = bid * 256 + threadIdx.x;
        int d = idx >> 9, k = idx & 511;
        float f = 0.f;
        if (k < 484) {
            int c = k / 121, rem = k % 121;   // rem = i*11 + j
            if (c == 0)      f = w_wt[d * 121 + rem];
            else if (c == 1) f = w_cwt[d * 121 + rem];
            else if (c == 2) f = w_condwt[d * 121 + rem];
            else             f = w_condwt[(512 + d) * 121 + rem];
        }
        int ks = k >> 5, kl = k & 31;
        g_A_pack[(ks * 512 + d) * 32 + kl] = f2bf(f);
    } else if (bid < 3072) {
        int wid = ((bid - 1024) * 256 + threadIdx.x) >> 6;
        int lane = threadIdx.x & 63;
        if (wid >= 16 * 512) return;
        int b = wid >> 9, d = wid & 511;
        float acc = 0.f;
        for (int k = lane; k < 256; k += 64)  acc += state[b * 256 + k]    * w_state[d * 256 + k];
        for (int k = lane; k < 512; k += 64)  acc += context[b * 512 + k]  * w_ctx[d * 512 + k];
        for (int k = lane; k < 1024; k += 64) acc += cond_mem[b * 1024 + k] * w_cond[d * 1024 + k];
        for (int off = 32; off; off >>= 1) acc += __shfl_down(acc, off, 64);
        if (lane == 0) g_st[b * 512 + d] = acc;
    } else {
        int b = bid - 3072, tid = threadIdx.x;
        int lbl = label[b];
        float ev = embed_table[lbl * 256 + tid];   // tid < 256
        g_data[b * 1792 + tid] = ev;
        g_merged[b * 1024 + tid] = ev;
        for (int k = tid; k < 1024; k += 256)
            g_data[b * 1792 + 768 + k] = cond_mem[b * 1024 + k];
    }
}

// ---- MFMA im2col conv + st + encode_pro + tanh + energy ----
// grid: 1024 = b(16) x h(32) x pxh(2). block: 512 thr = 8 waves; wave wv owns
// d in [64wv,64wv+64) x 64 px. epro tile HALF-resident in LDS (256d x 64px bf16,
// 34.8KB): half-0 burst-copied before K-loop (R16-proven), half-1 copied between
// the two epilogue halves. Total LDS ~46.6KB -> 3 blocks/CU (vs R16's 2).
__global__ __launch_bounds__(512, 6) void k_conv_energy(
    const float* __restrict__ pre_w, const float* __restrict__ cum_w, const float* __restrict__ cond_w,
    const float* __restrict__ encode_pro, const float* __restrict__ w_energy)
{
    __shared__ __align__(16) u16 src[4][11][76];      // 4 ch, 11 halo rows, 74+pad (6.7KB)
    __shared__ __align__(16) u16 bchunk[64][40];      // single-buffered B^T chunk (5.1KB)
    __shared__ __align__(16) u16 epro_l[256 * 68];    // HALF epro tile bf16, pad 68 (34.8KB)

    const int blk = blockIdx.x;
    const int pxh = blk & 1;
    const int h = (blk >> 1) & 31;
    const int b = blk >> 6;
    const int px0 = pxh * 64;

    const int tid = threadIdx.x;
    const int lane = tid & 63, wv = tid >> 6;     // 8 waves
    const int lr = lane & 15, lg = lane >> 4;

    const float* epbase = encode_pro + (size_t)b * 512 * 4096 + h * 128 + px0;

    // 1) epro HALF-0 burst copy: [256 d][64 px] f32 -> bf16 LDS (R16 pattern)
#pragma unroll
    for (int i = 0; i < 8; ++i) {
        int o = i * 2048 + tid * 4;            // flat float idx in 256x64 half-tile
        int r = o >> 6, c = o & 63;
        float4 v = *reinterpret_cast<const float4*>(&epbase[(size_t)r * 4096 + c]);
        ushort4 s;
        s.x = f2bf(v.x); s.y = f2bf(v.y); s.z = f2bf(v.z); s.w = f2bf(v.w);
        *reinterpret_cast<ushort4*>(&epro_l[r * 68 + c]) = s;
    }

    // 2) stage src images (f32 -> bf16), zero halo; x in [0,76) maps to w = px0-5+x
#pragma unroll
    for (int it = 0; it < 7; ++it) {
        int t = tid + it * 512;
        if (t < 4 * 11 * 76) {
            int c = t / (11 * 76);
            int rem = t % (11 * 76);
            int i = rem / 76, x = rem % 76;
            int row = h + i - 5, w = px0 - 5 + x;
            u16 v = 0;
            if (x < 74 && row >= 0 && row < 32 && w >= 0 && w < 128) {
                const float* img = (c == 0) ? pre_w + b * 4096
                                 : (c == 1) ? cum_w + b * 4096
                                 : (c == 2) ? cond_w + b * 8192
                                            : cond_w + b * 8192 + 4096;
                v = f2bf(img[row * 128 + w]);
            }
            src[c][i][x] = v;
        }
    }
    __syncthreads();

    // build macro: 64 px x 32 k for K-step KS into the single bchunk buffer
    const int kl = tid & 31;
    const int n0 = tid >> 5;   // 0..15
#define BUILD(KS)                                                               \
    {                                                                           \
        int kg = (KS) * 32 + kl;                                                \
        int c = 0, i = 0, jj = 0;                                               \
        bool ok = (kg < 484);                                                   \
        if (ok) { c = kg / 121; int r2 = kg % 121; i = r2 / 11; jj = r2 % 11; } \
        _Pragma("unroll")                                                       \
        for (int rep = 0; rep < 4; ++rep) {                                     \
            int n = n0 + rep * 16;                                              \
            bchunk[n][kl] = ok ? src[c][i][n + jj] : (u16)0;                    \
        }                                                                       \
    }

    f32x4 acc[4][4];
#pragma unroll
    for (int mt = 0; mt < 4; ++mt)
#pragma unroll
        for (int nt = 0; nt < 4; ++nt) {
            f32x4 z = {0.f, 0.f, 0.f, 0.f};
            acc[mt][nt] = z;
        }

    BUILD(0);
    __syncthreads();

    for (int ks = 0; ks < 16; ++ks) {
        bf16x8 afr[4];
#pragma unroll
        for (int mt = 0; mt < 4; ++mt) {
            int d = wv * 64 + mt * 16 + lr;
            afr[mt] = *reinterpret_cast<const bf16x8*>(&g_A_pack[(ks * 512 + d) * 32 + lg * 8]);
        }
        bf16x8 bfr[4];
#pragma unroll
        for (int nt = 0; nt < 4; ++nt)
            bfr[nt] = *reinterpret_cast<const bf16x8*>(&bchunk[nt * 16 + lr][lg * 8]);

#pragma unroll
        for (int mt = 0; mt < 4; ++mt)
#pragma unroll
            for (int nt = 0; nt < 4; ++nt)
                acc[mt][nt] = __builtin_amdgcn_mfma_f32_16x16x32_bf16(afr[mt], bfr[nt], acc[mt][nt], 0, 0, 0);
        __syncthreads();                 // all bchunk reads drained
        if (ks < 15) {
            BUILD(ks + 1);
            __syncthreads();             // writes visible before next reads
        }
    }
#undef BUILD

    // epilogue phase A: waves 0-3 (d < 256) use resident half-0
    float e[4] = {0.f, 0.f, 0.f, 0.f};
    if (wv < 4) {
#pragma unroll
        for (int mt = 0; mt < 4; ++mt) {
#pragma unroll
            for (int r = 0; r < 4; ++r) {
                int d = wv * 64 + mt * 16 + lg * 4 + r;       // 0..255
                float stv = g_st[b * 512 + d];
                float wev = w_energy[d];
#pragma unroll
                for (int nt = 0; nt < 4; ++nt) {
                    int px = nt * 16 + lr;
                    float val = stv + acc[mt][nt][r] + bf2f(epro_l[d * 68 + px]);
                    e[nt] += wev * fast_tanh(val);
                }
            }
        }
    }
    __syncthreads();   // half-0 reads complete before overwrite

    // epilogue phase B: all threads copy epro HALF-1 (d 256..511) into epro_l
#pragma unroll
    for (int i = 0; i < 8; ++i) {
        int o = i * 2048 + tid * 4;
        int r = o >> 6, c = o & 63;
        float4 v = *reinterpret_cast<const float4*>(&epbase[(size_t)(256 + r) * 4096 + c]);
        ushort4 s;
        s.x = f2bf(v.x); s.y = f2bf(v.y); s.z = f2bf(v.z); s.w = f2bf(v.w);
        *reinterpret_cast<ushort4*>(&epro_l[r * 68 + c]) = s;
    }
    __syncthreads();

    // epilogue phase C: waves 4-7 (d >= 256) use half-1
    if (wv >= 4) {
#pragma unroll
        for (int mt = 0; mt < 4; ++mt) {
#pragma unroll
            for (int r = 0; r < 4; ++r) {
                int d = wv * 64 + mt * 16 + lg * 4 + r;       // 256..511
                float stv = g_st[b * 512 + d];
                float wev = w_energy[d];
#pragma unroll
                for (int nt = 0; nt < 4; ++nt) {
                    int px = nt * 16 + lr;
                    float val = stv + acc[mt][nt][r] + bf2f(epro_l[(d - 256) * 68 + px]);
                    e[nt] += wev * fast_tanh(val);
                }
            }
        }
    }

    // phase D: reduce all 8 waves' partials (ered aliases bchunk, dead since K-loop)
    float* ered = reinterpret_cast<float*>(&bchunk[0][0]);   // [8][64]
    __syncthreads();
#pragma unroll
    for (int nt = 0; nt < 4; ++nt) {
        float v = e[nt];
        v += __shfl_xor(v, 16, 64);
        v += __shfl_xor(v, 32, 64);
        if (lane < 16) ered[wv * 64 + nt * 16 + lane] = v;
    }
    __syncthreads();
    if (tid < 64) {
        float v = 0.f;
#pragma unroll
        for (int w = 0; w < 8; ++w) v += ered[w * 64 + tid];
        g_eraw[b * 4096 + h * 128 + px0 + tid] = v;
    }
}

// ---- softmax over 4096 per batch: add mask, softmax g_eraw -> g_energ ----
__global__ void k_softmax(const float* __restrict__ encode_mask) {
    __shared__ float red[256];
    int b = blockIdx.x, tid = threadIdx.x;
    float v[16];
    float mx = -1e30f;
#pragma unroll
    for (int i = 0; i < 16; ++i) {
        int idx = b * 4096 + tid + i * 256;
        float ev = g_eraw[idx] + (encode_mask[idx] - 1.0f) * 1e8f;
        v[i] = ev; mx = fmaxf(mx, ev);
    }
    red[tid] = mx; __syncthreads();
    for (int s = 128; s; s >>= 1) { if (tid < s) red[tid] = fmaxf(red[tid], red[tid + s]); __syncthreads(); }
    mx = red[0]; __syncthreads();
    float sum = 0.f;
#pragma unroll
    for (int i = 0; i < 16; ++i) { v[i] = __expf(v[i] - mx); sum += v[i]; }
    red[tid] = sum; __syncthreads();
    for (int s = 128; s; s >>= 1) { if (tid < s) red[tid] += red[tid + s]; __syncthreads(); }
    float inv = 1.0f / red[0];
#pragma unroll
    for (int i = 0; i < 16; ++i) g_energ[b * 4096 + tid + i * 256] = v[i] * inv;
}

// ---- ctx[b,c] = sum_hw encode[b,c,hw] * att[b,hw]; write into data & merged ----
__global__ void k_ctx(const float* __restrict__ encode) {
    int wid = (blockIdx.x * blockDim.x + threadIdx.x) >> 6;
    int lane = threadIdx.x & 63;
    if (wid >= 16 * 512) return;
    int b = wid >> 9, c = wid & 511;
    const float* e = encode + (size_t)wid * 4096;
    const float* a = g_energ + b * 4096;
    float acc = 0.f;
#pragma unroll
    for (int it = 0; it < 16; ++it) {
        int base = it * 256 + lane * 4;
        float4 ev = *reinterpret_cast<const float4*>(&e[base]);
        float4 av = *reinterpret_cast<const float4*>(&a[base]);
        acc += ev.x * av.x + ev.y * av.y + ev.z * av.z + ev.w * av.w;
    }
    for (int off = 32; off; off >>= 1) acc += __shfl_down(acc, off, 64);
    if (lane == 0) { g_data[b * 1792 + 256 + c] = acc; g_merged[b * 1024 + 512 + c] = acc; }
}

// ---- E1: gates (update, reset) and i2s linear part ----
__global__ void k_e1(const float* __restrict__ state,
                     const float* __restrict__ w_i2g, const float* __restrict__ b_i2g,
                     const float* __restrict__ w_s2g, const float* __restrict__ w_i2s,
                     const float* __restrict__ b_i2s) {
    int wid = (blockIdx.x * blockDim.x + threadIdx.x) >> 6;
    int lane = threadIdx.x & 63;
    if (wid >= 16 * 768) return;
    int b = wid / 768, o = wid % 768;
    const float* dt = g_data + b * 1792;
    float acc = 0.f;
    if (o < 512) {
        const float* wr = w_i2g + o * 1792;
        for (int k = lane; k < 1792; k += 64) acc += dt[k] * wr[k];
        const float* wsg = w_s2g + o * 256;
        for (int k = lane; k < 256; k += 64) acc += state[b * 256 + k] * wsg[k];
    } else {
        const float* wr = w_i2s + (o - 512) * 1792;
        for (int k = lane; k < 1792; k += 64) acc += dt[k] * wr[k];
    }
    for (int off = 32; off; off >>= 1) acc += __shfl_down(acc, off, 64);
    if (lane == 0) {
        if (o < 256)       g_update[b * 256 + o]        = sigmoidf_(acc + b_i2g[o]);
        else if (o < 512)  g_reset[b * 256 + (o - 256)] = sigmoidf_(acc + b_i2g[o]);
        else               g_i2s[b * 256 + (o - 512)]   = acc + b_i2s[o - 512];
    }
}

// ---- E2: state_hat + new_state -> merged[256:512] ----
__global__ void k_e2(const float* __restrict__ state, const float* __restrict__ w_h2h) {
    int wid = (blockIdx.x * blockDim.x + threadIdx.x) >> 6;
    int lane = threadIdx.x & 63;
    if (wid >= 16 * 256) return;
    int b = wid >> 8, d = wid & 255;
    const float* wr = w_h2h + d * 256;
    float acc = 0.f;
    for (int k = lane; k < 256; k += 64)
        acc += state[b * 256 + k] * g_reset[b * 256 + k] * wr[k];
    for (int off = 32; off; off >>= 1) acc += __shfl_down(acc, off, 64);
    if (lane == 0) {
        float sh = fast_tanh(g_i2s[b * 256 + d] + acc);
        float u = g_update[b * 256 + d];
        g_merged[b * 1024 + 256 + d] = u * sh + (1.f - u) * state[b * 256 + d];
    }
}

// ---- E3: hid = relu(merged @ w_l1.T + b_l1) ----
__global__ void k_e3(const float* __restrict__ w_l1, const float* __restrict__ b_l1) {
    int wid = (blockIdx.x * blockDim.x + threadIdx.x) >> 6;
    int lane = threadIdx.x & 63;
    if (wid >= 16 * 512) return;
    int b = wid >> 9, m = wid & 511;
    const float* mg = g_merged + b * 1024;
    const float* wr = w_l1 + m * 1024;
    float acc = 0.f;
    for (int k = lane; k < 1024; k += 64) acc += mg[k] * wr[k];
    for (int off = 32; off; off >>= 1) acc += __shfl_down(acc, off, 64);
    if (lane == 0) g_hid[b * 512 + m] = fmaxf(acc + b_l1[m], 0.f);
}

// ---- E4: readout = hid @ w_l2.T + b_l2 -> f32 out ----
__global__ void k_e4(const float* __restrict__ w_l2, const float* __restrict__ b_l2,
                     float* __restrict__ out) {
    int wid = (blockIdx.x * blockDim.x + threadIdx.x) >> 6;
    int lane = threadIdx.x & 63;
    if (wid >= 16 * 1000) return;
    int b = wid / 1000, v = wid % 1000;
    const float* hd = g_hid + b * 512;
    const float* wr = w_l2 + v * 512;
    float acc = 0.f;
    for (int k = lane; k < 512; k += 64) acc += hd[k] * wr[k];
    for (int off = 32; off; off >>= 1) acc += __shfl_down(acc, off, 64);
    if (lane == 0) out[b * 1000 + v] = acc + b_l2[v];
}

extern "C" void kernel_launch(void* const* d_in, const int* in_sizes, int n_in,
                              void* d_out, int out_size, void* d_ws, size_t ws_size,
                              hipStream_t stream) {
    // ---- input-order guard (proven passing in R6-R18) ----
    static const int EXP[28] = {
        33554432, 33554432, 65536, 4096, 65536, 65536, 8192, 16384, 131072, 16,
        61952, 61952, 123904, 512, 131072, 262144, 524288, 458752, 256, 917504,
        512, 131072, 65536, 256000, 524288, 512, 512000, 1000};
    if (n_in != 28) return;
    for (int i = 0; i < 28; ++i)
        if (in_sizes[i] != EXP[i]) return;

    const float* encode      = (const float*)d_in[0];
    const float* encode_pro  = (const float*)d_in[1];
    const float* encode_mask = (const float*)d_in[2];
    const float* state       = (const float*)d_in[3];
    const float* pre_weight  = (const float*)d_in[4];
    const float* cum_weight  = (const float*)d_in[5];
    const float* context     = (const float*)d_in[6];
    const float* cond_mem    = (const float*)d_in[7];
    const float* cond_weight = (const float*)d_in[8];
    const int*   label_id    = (const int*)d_in[9];
    const float* w_wt     = (const float*)d_in[10];
    const float* w_cwt    = (const float*)d_in[11];
    const float* w_condwt = (const float*)d_in[12];
    const float* w_energy = (const float*)d_in[13];
    const float* w_state  = (const float*)d_in[14];
    const float* w_ctx    = (const float*)d_in[15];
    const float* w_cond   = (const float*)d_in[16];
    const float* w_i2s    = (const float*)d_in[17];
    const float* b_i2s    = (const float*)d_in[18];
    const float* w_i2g    = (const float*)d_in[19];
    const float* b_i2g    = (const float*)d_in[20];
    const float* w_s2g    = (const float*)d_in[21];
    const float* w_h2h    = (const float*)d_in[22];
    const float* embed_t  = (const float*)d_in[23];
    const float* w_l1     = (const float*)d_in[24];
    const float* b_l1     = (const float*)d_in[25];
    const float* w_l2     = (const float*)d_in[26];
    const float* b_l2     = (const float*)d_in[27];
    float* out = (float*)d_out;
    (void)d_ws; (void)ws_size;

    k_pre<<<3088, 256, 0, stream>>>(w_wt, w_cwt, w_condwt, state, context, cond_mem,
                                    w_state, w_ctx, w_cond, label_id, embed_t);
    k_conv_energy<<<1024, 512, 0, stream>>>(pre_weight, cum_weight, cond_weight,
                                            encode_pro, w_energy);
    k_softmax<<<16, 256, 0, stream>>>(encode_mask);
    k_ctx<<<2048, 256, 0, stream>>>(encode);
    k_e1<<<3072, 256, 0, stream>>>(state, w_i2g, b_i2g, w_s2g, w_i2s, b_i2s);
    k_e2<<<1024, 256, 0, stream>>>(state, w_h2h);
    k_e3<<<2048, 256, 0, stream>>>(w_l1, b_l1);
    k_e4<<<4000, 256, 0, stream>>>(w_l2, b_l2, out);
}

// Round 20
// 160.941 us; speedup vs baseline: 2.3522x; 2.3522x over previous
//
#include <hip/hip_runtime.h>
#include <math.h>

typedef unsigned short u16;
typedef __bf16 bf16x8 __attribute__((ext_vector_type(8)));
typedef float f32x4 __attribute__((ext_vector_type(4)));

// ---- all scratch in device globals: zero dependence on ws_size ----
__device__ u16   g_A_pack[16 * 512 * 32];  // bf16 conv weights, swizzled [ks][d][kl]
__device__ float g_st[16 * 512];
__device__ float g_eraw[16 * 4096];        // raw energies (pre-mask, pre-softmax)
__device__ float g_data[16 * 1792];
__device__ float g_merged[16 * 1024];
__device__ float g_update[16 * 256];
__device__ float g_reset[16 * 256];
__device__ float g_i2s[16 * 256];
__device__ float g_hid[16 * 512];

__device__ __forceinline__ u16 f2bf(float f) {
    unsigned u = __float_as_uint(f);
    u = (u + 0x7FFFu + ((u >> 16) & 1u)) >> 16;
    return (u16)u;
}
__device__ __forceinline__ float bf2f(u16 u) {
    return __uint_as_float(((unsigned)u) << 16);
}
__device__ __forceinline__ float fast_tanh(float x) {
    return 1.0f - 2.0f / (__expf(2.0f * x) + 1.0f);
}
__device__ __forceinline__ float sigmoidf_(float x) {
    return 1.0f / (1.0f + __expf(-x));
}

// ---- fused pre-pass: [0,1024) weight pack | [1024,3072) st GEMV | [3072,3088) e0 ----
__global__ void k_pre(const float* __restrict__ w_wt, const float* __restrict__ w_cwt,
                      const float* __restrict__ w_condwt, const float* __restrict__ state,
                      const float* __restrict__ context, const float* __restrict__ cond_mem,
                      const float* __restrict__ w_state, const float* __restrict__ w_ctx,
                      const float* __restrict__ w_cond, const int* __restrict__ label,
                      const float* __restrict__ embed_table) {
    int bid = blockIdx.x;
    if (bid < 1024) {
        int idx = bid * 256 + threadIdx.x;
        int d = idx >> 9, k = idx & 511;
        float f = 0.f;
        if (k < 484) {
            int c = k / 121, rem = k % 121;   // rem = i*11 + j
            if (c == 0)      f = w_wt[d * 121 + rem];
            else if (c == 1) f = w_cwt[d * 121 + rem];
            else if (c == 2) f = w_condwt[d * 121 + rem];
            else             f = w_condwt[(512 + d) * 121 + rem];
        }
        int ks = k >> 5, kl = k & 31;
        g_A_pack[(ks * 512 + d) * 32 + kl] = f2bf(f);
    } else if (bid < 3072) {
        int wid = ((bid - 1024) * 256 + threadIdx.x) >> 6;
        int lane = threadIdx.x & 63;
        if (wid >= 16 * 512) return;
        int b = wid >> 9, d = wid & 511;
        float acc = 0.f;
        for (int k = lane; k < 256; k += 64)  acc += state[b * 256 + k]    * w_state[d * 256 + k];
        for (int k = lane; k < 512; k += 64)  acc += context[b * 512 + k]  * w_ctx[d * 512 + k];
        for (int k = lane; k < 1024; k += 64) acc += cond_mem[b * 1024 + k] * w_cond[d * 1024 + k];
        for (int off = 32; off; off >>= 1) acc += __shfl_down(acc, off, 64);
        if (lane == 0) g_st[b * 512 + d] = acc;
    } else {
        int b = bid - 3072, tid = threadIdx.x;
        int lbl = label[b];
        float ev = embed_table[lbl * 256 + tid];   // tid < 256
        g_data[b * 1792 + tid] = ev;
        g_merged[b * 1024 + tid] = ev;
        for (int k = tid; k < 1024; k += 256)
            g_data[b * 1792 + 768 + k] = cond_mem[b * 1024 + k];
    }
}

// ---- MFMA im2col conv + st + encode_pro + tanh + energy (R16-proven, verbatim) ----
// grid: 1024 = b(16) x h(32) x pxh(2). block: 512 thr = 8 waves; wave wv owns
// d in [64wv,64wv+64) x 64 px. epro tile bf16 in LDS (68KB), burst-copied at
// block start. LDS 80KB -> 2 blocks/CU; (512,4) keeps VGPR=64, no spill.
__global__ __launch_bounds__(512, 4) void k_conv_energy(
    const float* __restrict__ pre_w, const float* __restrict__ cum_w, const float* __restrict__ cond_w,
    const float* __restrict__ encode_pro, const float* __restrict__ w_energy)
{
    __shared__ __align__(16) u16 src[4][11][76];      // 4 ch, 11 halo rows, 74+pad (6.7KB)
    __shared__ __align__(16) u16 bchunk[64][40];      // single-buffered B^T chunk (5.1KB)
    __shared__ __align__(16) u16 epro_l[512 * 68];    // epro tile bf16, pad 68 (68KB)

    const int blk = blockIdx.x;
    const int pxh = blk & 1;
    const int h = (blk >> 1) & 31;
    const int b = blk >> 6;
    const int px0 = pxh * 64;

    const int tid = threadIdx.x;
    const int lane = tid & 63, wv = tid >> 6;     // 8 waves
    const int lr = lane & 15, lg = lane >> 4;

    // 1) epro tile: [512 d][64 px] f32 -> bf16 in LDS, coalesced float4 loads
    {
        const float* epbase = encode_pro + (size_t)b * 512 * 4096 + h * 128 + px0;
#pragma unroll
        for (int i = 0; i < 16; ++i) {
            int o = i * 2048 + tid * 4;            // flat float idx in 512x64 tile
            int r = o >> 6, c = o & 63;
            float4 v = *reinterpret_cast<const float4*>(&epbase[(size_t)r * 4096 + c]);
            ushort4 s;
            s.x = f2bf(v.x); s.y = f2bf(v.y); s.z = f2bf(v.z); s.w = f2bf(v.w);
            *reinterpret_cast<ushort4*>(&epro_l[r * 68 + c]) = s;   // 8B aligned (136B stride)
        }
    }

    // 2) stage src images (f32 -> bf16), zero halo; x in [0,76) maps to w = px0-5+x
#pragma unroll
    for (int it = 0; it < 7; ++it) {
        int t = tid + it * 512;
        if (t < 4 * 11 * 76) {
            int c = t / (11 * 76);
            int rem = t % (11 * 76);
            int i = rem / 76, x = rem % 76;
            int row = h + i - 5, w = px0 - 5 + x;
            u16 v = 0;
            if (x < 74 && row >= 0 && row < 32 && w >= 0 && w < 128) {
                const float* img = (c == 0) ? pre_w + b * 4096
                                 : (c == 1) ? cum_w + b * 4096
                                 : (c == 2) ? cond_w + b * 8192
                                            : cond_w + b * 8192 + 4096;
                v = f2bf(img[row * 128 + w]);
            }
            src[c][i][x] = v;
        }
    }
    __syncthreads();

    // build macro: 64 px x 32 k for K-step KS into the single bchunk buffer
    const int kl = tid & 31;
    const int n0 = tid >> 5;   // 0..15
#define BUILD(KS)                                                               \
    {                                                                           \
        int kg = (KS) * 32 + kl;                                                \
        int c = 0, i = 0, jj = 0;                                               \
        bool ok = (kg < 484);                                                   \
        if (ok) { c = kg / 121; int r2 = kg % 121; i = r2 / 11; jj = r2 % 11; } \
        _Pragma("unroll")                                                       \
        for (int rep = 0; rep < 4; ++rep) {                                     \
            int n = n0 + rep * 16;                                              \
            bchunk[n][kl] = ok ? src[c][i][n + jj] : (u16)0;                    \
        }                                                                       \
    }

    f32x4 acc[4][4];
#pragma unroll
    for (int mt = 0; mt < 4; ++mt)
#pragma unroll
        for (int nt = 0; nt < 4; ++nt) {
            f32x4 z = {0.f, 0.f, 0.f, 0.f};
            acc[mt][nt] = z;
        }

    BUILD(0);
    __syncthreads();

    for (int ks = 0; ks < 16; ++ks) {
        bf16x8 afr[4];
#pragma unroll
        for (int mt = 0; mt < 4; ++mt) {
            int d = wv * 64 + mt * 16 + lr;
            afr[mt] = *reinterpret_cast<const bf16x8*>(&g_A_pack[(ks * 512 + d) * 32 + lg * 8]);
        }
        bf16x8 bfr[4];
#pragma unroll
        for (int nt = 0; nt < 4; ++nt)
            bfr[nt] = *reinterpret_cast<const bf16x8*>(&bchunk[nt * 16 + lr][lg * 8]);

#pragma unroll
        for (int mt = 0; mt < 4; ++mt)
#pragma unroll
            for (int nt = 0; nt < 4; ++nt)
                acc[mt][nt] = __builtin_amdgcn_mfma_f32_16x16x32_bf16(afr[mt], bfr[nt], acc[mt][nt], 0, 0, 0);
        __syncthreads();                 // all bchunk reads drained
        if (ks < 15) {
            BUILD(ks + 1);
            __syncthreads();             // writes visible before next reads
        }
    }
#undef BUILD

    // epilogue: e[px] += w_energy[d] * tanh(st + conv + epro); epro bf16 from LDS
    float e[4] = {0.f, 0.f, 0.f, 0.f};
#pragma unroll
    for (int mt = 0; mt < 4; ++mt) {
#pragma unroll
        for (int r = 0; r < 4; ++r) {
            int d = wv * 64 + mt * 16 + lg * 4 + r;       // 0..511
            float stv = g_st[b * 512 + d];
            float wev = w_energy[d];
#pragma unroll
            for (int nt = 0; nt < 4; ++nt) {
                int px = nt * 16 + lr;
                float val = stv + acc[mt][nt][r] + bf2f(epro_l[d * 68 + px]);
                e[nt] += wev * fast_tanh(val);
            }
        }
    }

    // ered aliases bchunk (dead after K-loop; barrier below orders reuse)
    float* ered = reinterpret_cast<float*>(&bchunk[0][0]);   // [8][64]
    __syncthreads();
#pragma unroll
    for (int nt = 0; nt < 4; ++nt) {
        float v = e[nt];
        v += __shfl_xor(v, 16, 64);
        v += __shfl_xor(v, 32, 64);
        if (lane < 16) ered[wv * 64 + nt * 16 + lane] = v;
    }
    __syncthreads();
    if (tid < 64) {
        float v = 0.f;
#pragma unroll
        for (int w = 0; w < 8; ++w) v += ered[w * 64 + tid];
        g_eraw[b * 4096 + h * 128 + px0 + tid] = v;
    }
}

// ---- fused softmax + ctx: grid 512 = b(16) x cchunk(32; 16 c each), block 256 ----
// Each block recomputes batch-b softmax (deterministic) into LDS, then dots its
// 16 encode rows against it. Removes the separate softmax dispatch + att round-trip.
__global__ __launch_bounds__(256) void k_ctx(const float* __restrict__ encode,
                                             const float* __restrict__ encode_mask) {
    __shared__ float att[4096];    // 16KB
    __shared__ float red[256];

    const int bid = blockIdx.x;
    const int b = bid >> 5;
    const int c0 = (bid & 31) * 16;
    const int tid = threadIdx.x;
    const int lane = tid & 63, wvi = tid >> 6;   // 4 waves

    // softmax of g_eraw[b] + mask into att[]
    float v[16];
    float mx = -1e30f;
#pragma unroll
    for (int i = 0; i < 16; ++i) {
        int idx = tid + i * 256;
        float ev = g_eraw[b * 4096 + idx] + (encode_mask[b * 4096 + idx] - 1.0f) * 1e8f;
        v[i] = ev; mx = fmaxf(mx, ev);
    }
    red[tid] = mx; __syncthreads();
    for (int s = 128; s; s >>= 1) { if (tid < s) red[tid] = fmaxf(red[tid], red[tid + s]); __syncthreads(); }
    mx = red[0]; __syncthreads();
    float sum = 0.f;
#pragma unroll
    for (int i = 0; i < 16; ++i) { v[i] = __expf(v[i] - mx); sum += v[i]; }
    red[tid] = sum; __syncthreads();
    for (int s = 128; s; s >>= 1) { if (tid < s) red[tid] += red[tid + s]; __syncthreads(); }
    float inv = 1.0f / red[0];
#pragma unroll
    for (int i = 0; i < 16; ++i) att[tid + i * 256] = v[i] * inv;
    __syncthreads();

    // dot phase: wave wvi handles c = c0 + wvi*4 + {0..3}
#pragma unroll
    for (int cc = 0; cc < 4; ++cc) {
        int c = c0 + wvi * 4 + cc;
        const float* e = encode + ((size_t)b * 512 + c) * 4096;
        float acc = 0.f;
#pragma unroll
        for (int it = 0; it < 16; ++it) {
            int base = it * 256 + lane * 4;
            float4 ev = *reinterpret_cast<const float4*>(&e[base]);
            float4 av = *reinterpret_cast<const float4*>(&att[base]);
            acc += ev.x * av.x + ev.y * av.y + ev.z * av.z + ev.w * av.w;
        }
        for (int off = 32; off; off >>= 1) acc += __shfl_down(acc, off, 64);
        if (lane == 0) { g_data[b * 1792 + 256 + c] = acc; g_merged[b * 1024 + 512 + c] = acc; }
    }
}

// ---- E1: gates (update, reset) and i2s linear part ----
__global__ void k_e1(const float* __restrict__ state,
                     const float* __restrict__ w_i2g, const float* __restrict__ b_i2g,
                     const float* __restrict__ w_s2g, const float* __restrict__ w_i2s,
                     const float* __restrict__ b_i2s) {
    int wid = (blockIdx.x * blockDim.x + threadIdx.x) >> 6;
    int lane = threadIdx.x & 63;
    if (wid >= 16 * 768) return;
    int b = wid / 768, o = wid % 768;
    const float* dt = g_data + b * 1792;
    float acc = 0.f;
    if (o < 512) {
        const float* wr = w_i2g + o * 1792;
        for (int k = lane; k < 1792; k += 64) acc += dt[k] * wr[k];
        const float* wsg = w_s2g + o * 256;
        for (int k = lane; k < 256; k += 64) acc += state[b * 256 + k] * wsg[k];
    } else {
        const float* wr = w_i2s + (o - 512) * 1792;
        for (int k = lane; k < 1792; k += 64) acc += dt[k] * wr[k];
    }
    for (int off = 32; off; off >>= 1) acc += __shfl_down(acc, off, 64);
    if (lane == 0) {
        if (o < 256)       g_update[b * 256 + o]        = sigmoidf_(acc + b_i2g[o]);
        else if (o < 512)  g_reset[b * 256 + (o - 256)] = sigmoidf_(acc + b_i2g[o]);
        else               g_i2s[b * 256 + (o - 512)]   = acc + b_i2s[o - 512];
    }
}

// ---- E2: state_hat + new_state -> merged[256:512] ----
__global__ void k_e2(const float* __restrict__ state, const float* __restrict__ w_h2h) {
    int wid = (blockIdx.x * blockDim.x + threadIdx.x) >> 6;
    int lane = threadIdx.x & 63;
    if (wid >= 16 * 256) return;
    int b = wid >> 8, d = wid & 255;
    const float* wr = w_h2h + d * 256;
    float acc = 0.f;
    for (int k = lane; k < 256; k += 64)
        acc += state[b * 256 + k] * g_reset[b * 256 + k] * wr[k];
    for (int off = 32; off; off >>= 1) acc += __shfl_down(acc, off, 64);
    if (lane == 0) {
        float sh = fast_tanh(g_i2s[b * 256 + d] + acc);
        float u = g_update[b * 256 + d];
        g_merged[b * 1024 + 256 + d] = u * sh + (1.f - u) * state[b * 256 + d];
    }
}

// ---- E3: hid = relu(merged @ w_l1.T + b_l1) ----
__global__ void k_e3(const float* __restrict__ w_l1, const float* __restrict__ b_l1) {
    int wid = (blockIdx.x * blockDim.x + threadIdx.x) >> 6;
    int lane = threadIdx.x & 63;
    if (wid >= 16 * 512) return;
    int b = wid >> 9, m = wid & 511;
    const float* mg = g_merged + b * 1024;
    const float* wr = w_l1 + m * 1024;
    float acc = 0.f;
    for (int k = lane; k < 1024; k += 64) acc += mg[k] * wr[k];
    for (int off = 32; off; off >>= 1) acc += __shfl_down(acc, off, 64);
    if (lane == 0) g_hid[b * 512 + m] = fmaxf(acc + b_l1[m], 0.f);
}

// ---- E4: readout = hid @ w_l2.T + b_l2 -> f32 out ----
__global__ void k_e4(const float* __restrict__ w_l2, const float* __restrict__ b_l2,
                     float* __restrict__ out) {
    int wid = (blockIdx.x * blockDim.x + threadIdx.x) >> 6;
    int lane = threadIdx.x & 63;
    if (wid >= 16 * 1000) return;
    int b = wid / 1000, v = wid % 1000;
    const float* hd = g_hid + b * 512;
    const float* wr = w_l2 + v * 512;
    float acc = 0.f;
    for (int k = lane; k < 512; k += 64) acc += hd[k] * wr[k];
    for (int off = 32; off; off >>= 1) acc += __shfl_down(acc, off, 64);
    if (lane == 0) out[b * 1000 + v] = acc + b_l2[v];
}

extern "C" void kernel_launch(void* const* d_in, const int* in_sizes, int n_in,
                              void* d_out, int out_size, void* d_ws, size_t ws_size,
                              hipStream_t stream) {
    // ---- input-order guard (proven passing in R6-R19) ----
    static const int EXP[28] = {
        33554432, 33554432, 65536, 4096, 65536, 65536, 8192, 16384, 131072, 16,
        61952, 61952, 123904, 512, 131072, 262144, 524288, 458752, 256, 917504,
        512, 131072, 65536, 256000, 524288, 512, 512000, 1000};
    if (n_in != 28) return;
    for (int i = 0; i < 28; ++i)
        if (in_sizes[i] != EXP[i]) return;

    const float* encode      = (const float*)d_in[0];
    const float* encode_pro  = (const float*)d_in[1];
    const float* encode_mask = (const float*)d_in[2];
    const float* state       = (const float*)d_in[3];
    const float* pre_weight  = (const float*)d_in[4];
    const float* cum_weight  = (const float*)d_in[5];
    const float* context     = (const float*)d_in[6];
    const float* cond_mem    = (const float*)d_in[7];
    const float* cond_weight = (const float*)d_in[8];
    const int*   label_id    = (const int*)d_in[9];
    const float* w_wt     = (const float*)d_in[10];
    const float* w_cwt    = (const float*)d_in[11];
    const float* w_condwt = (const float*)d_in[12];
    const float* w_energy = (const float*)d_in[13];
    const float* w_state  = (const float*)d_in[14];
    const float* w_ctx    = (const float*)d_in[15];
    const float* w_cond   = (const float*)d_in[16];
    const float* w_i2s    = (const float*)d_in[17];
    const float* b_i2s    = (const float*)d_in[18];
    const float* w_i2g    = (const float*)d_in[19];
    const float* b_i2g    = (const float*)d_in[20];
    const float* w_s2g    = (const float*)d_in[21];
    const float* w_h2h    = (const float*)d_in[22];
    const float* embed_t  = (const float*)d_in[23];
    const float* w_l1     = (const float*)d_in[24];
    const float* b_l1     = (const float*)d_in[25];
    const float* w_l2     = (const float*)d_in[26];
    const float* b_l2     = (const float*)d_in[27];
    float* out = (float*)d_out;
    (void)d_ws; (void)ws_size;

    k_pre<<<3088, 256, 0, stream>>>(w_wt, w_cwt, w_condwt, state, context, cond_mem,
                                    w_state, w_ctx, w_cond, label_id, embed_t);
    k_conv_energy<<<1024, 512, 0, stream>>>(pre_weight, cum_weight, cond_weight,
                                            encode_pro, w_energy);
    k_ctx<<<512, 256, 0, stream>>>(encode, encode_mask);
    k_e1<<<3072, 256, 0, stream>>>(state, w_i2g, b_i2g, w_s2g, w_i2s, b_i2s);
    k_e2<<<1024, 256, 0, stream>>>(state, w_h2h);
    k_e3<<<2048, 256, 0, stream>>>(w_l1, b_l1);
    k_e4<<<4000, 256, 0, stream>>>(w_l2, b_l2, out);
}